// Round 2
// baseline (2929.819 us; speedup 1.0000x reference)
//
#include <hip/hip_runtime.h>
#include <hip/hip_bf16.h>

__device__ __forceinline__ void atomicMaxFloat(float* addr, float val) {
    if (val >= 0.f) atomicMax((int*)addr, __float_as_int(val));
    else            atomicMin((unsigned int*)addr, __float_as_uint(val));
}

// ---------------------------------------------------------------- K0: init
// M[8][16] = W_edge_att(8x64) @ W_edge(64x16)
// G[64][128]: G[h*8+k][i] = sum_d W[(h*8+d)*128+i] * W_att[k*8+d]
// Also: probe edge_index for int64 layout (odd int32 words all zero).
__global__ __launch_bounds__(256) void init_kernel(
        const float* __restrict__ W, const float* __restrict__ W_edge,
        const float* __restrict__ W_edge_att, const float* __restrict__ W_att,
        const int* __restrict__ ei,
        float* __restrict__ G, float* __restrict__ M,
        float* __restrict__ maxh, float* __restrict__ sumh,
        int* __restrict__ flags) {
    int tid = threadIdx.x;
    if (tid < 128) {
        int h = tid >> 4, k = tid & 15;
        float acc = 0.f;
        for (int j = 0; j < 64; ++j)
            acc += W_edge_att[h * 64 + j] * W_edge[j * 16 + k];
        M[tid] = acc;
    }
    for (int idx = tid; idx < 64 * 128; idx += 256) {
        int l = idx >> 7, i = idx & 127;
        int h = l >> 3, k = l & 7;
        float acc = 0.f;
#pragma unroll
        for (int d = 0; d < 8; ++d)
            acc += W[(h * 8 + d) * 128 + i] * W_att[k * 8 + d];
        G[idx] = acc;
    }
    if (tid < 8) { maxh[tid] = -1e30f; sumh[tid] = 0.f; }
    if (tid == 0) {
        // int64 edge_index (values < 2^31): every odd int32 word is 0.
        int zc = 0;
        for (int i = 1; i < 128; i += 2) zc += (ei[i] == 0);
        flags[0] = (zc >= 60) ? 1 : 0;
    }
}

// ---------------------------------------------------------------- K1: g = x @ G.T  (+ zero agg)
__global__ __launch_bounds__(256) void g_kernel(
        const float* __restrict__ x, const float* __restrict__ G,
        float* __restrict__ g, float* __restrict__ agg, int N) {
    __shared__ float sG[64 * 129];   // +1 pad: kills stride-128 bank conflict
    __shared__ float sx[16 * 128];
    int tid = threadIdx.x;
    for (int idx = tid; idx < 64 * 128; idx += 256)
        sG[(idx >> 7) * 129 + (idx & 127)] = G[idx];
    int nbase = blockIdx.x * 16;
    {
        int i8 = tid * 8;                 // 2048 floats, 8 per thread
        int n = nbase + (i8 >> 7);
        if (n < N) {
            const float4* p = (const float4*)(x + (size_t)n * 128 + (i8 & 127));
            float4 v0 = p[0], v1 = p[1];
            sx[i8 + 0] = v0.x; sx[i8 + 1] = v0.y; sx[i8 + 2] = v0.z; sx[i8 + 3] = v0.w;
            sx[i8 + 4] = v1.x; sx[i8 + 5] = v1.y; sx[i8 + 6] = v1.z; sx[i8 + 7] = v1.w;
        } else {
#pragma unroll
            for (int j = 0; j < 8; ++j) sx[i8 + j] = 0.f;
        }
    }
    __syncthreads();
    for (int o = tid; o < 16 * 64; o += 256) {
        int nl = o >> 6, l = o & 63;
        int n = nbase + nl;
        if (n >= N) continue;
        float acc = 0.f;
        const float* gr = &sG[l * 129];
        const float* xr = &sx[nl * 128];
#pragma unroll
        for (int i = 0; i < 128; ++i) acc += xr[i] * gr[i];
        g[(size_t)n * 64 + l] = acc;
        agg[(size_t)n * 64 + l] = 0.f;    // zero agg for K3 (harness poisons ws)
    }
}

// ---------------------------------------------------------------- K2: per-edge alpha_raw + global per-head max
__global__ __launch_bounds__(256) void edge1_kernel(
        const float* __restrict__ edge_attr, const int* __restrict__ ei,
        const float* __restrict__ M, const float* __restrict__ g,
        float* __restrict__ alpha, float* __restrict__ maxh,
        const int* __restrict__ flags, int E) {
    __shared__ float sM[128];
    __shared__ float wmax[4][8];
    int tid = threadIdx.x;
    if (tid < 128) sM[tid] = M[tid];
    __syncthreads();
    int idx64 = flags[0];
    int e = blockIdx.x * 256 + tid;
    float a[8];
    if (e < E) {
        float at[16];
        const float4* p = (const float4*)(edge_attr + (size_t)e * 16);
        float4 v0 = p[0], v1 = p[1], v2 = p[2], v3 = p[3];
        at[0] = v0.x; at[1] = v0.y; at[2] = v0.z; at[3] = v0.w;
        at[4] = v1.x; at[5] = v1.y; at[6] = v1.z; at[7] = v1.w;
        at[8] = v2.x; at[9] = v2.y; at[10] = v2.z; at[11] = v2.w;
        at[12] = v3.x; at[13] = v3.y; at[14] = v3.z; at[15] = v3.w;
        int s, d;
        if (idx64) { s = ei[2 * (size_t)e]; d = ei[2 * ((size_t)E + e)]; }
        else       { s = ei[e];             d = ei[(size_t)E + e]; }
        const float4* gs = (const float4*)(g + (size_t)s * 64);
        const float4* gd = (const float4*)(g + (size_t)d * 64);
#pragma unroll
        for (int h = 0; h < 8; ++h) {
            float ea = 0.f;
#pragma unroll
            for (int k = 0; k < 16; ++k) ea += sM[h * 16 + k] * at[k];
            float4 a0 = gs[h * 2], a1 = gs[h * 2 + 1];
            float4 b0 = gd[h * 2], b1 = gd[h * 2 + 1];
            float dot = a0.x * b0.x + a0.y * b0.y + a0.z * b0.z + a0.w * b0.w
                      + a1.x * b1.x + a1.y * b1.y + a1.z * b1.z + a1.w * b1.w;
            float t = dot + 8.f * ea;                  // edge_term = ea * D
            a[h] = (t > 0.f) ? t : 0.2f * t;           // leaky_relu(0.2)
        }
        float4* ap = (float4*)(alpha + (size_t)e * 8);
        ap[0] = make_float4(a[0], a[1], a[2], a[3]);
        ap[1] = make_float4(a[4], a[5], a[6], a[7]);
    } else {
#pragma unroll
        for (int h = 0; h < 8; ++h) a[h] = -1e30f;
    }
    // wave -> block -> global max per head
#pragma unroll
    for (int h = 0; h < 8; ++h) {
        float m = a[h];
#pragma unroll
        for (int off = 32; off >= 1; off >>= 1)
            m = fmaxf(m, __shfl_xor(m, off, 64));
        a[h] = m;
    }
    int wave = tid >> 6, lane = tid & 63;
    if (lane == 0)
#pragma unroll
        for (int h = 0; h < 8; ++h) wmax[wave][h] = a[h];
    __syncthreads();
    if (tid < 8) {
        float m = fmaxf(fmaxf(wmax[0][tid], wmax[1][tid]),
                        fmaxf(wmax[2][tid], wmax[3][tid]));
        atomicMaxFloat(&maxh[tid], m);
    }
}

// ---------------------------------------------------------------- K3: w = exp(alpha-max); scatter w*g_dst; accumulate per-head sums
__global__ __launch_bounds__(256) void edge2_kernel(
        const int* __restrict__ ei, const float* __restrict__ g,
        const float* __restrict__ alpha, const float* __restrict__ maxh,
        float* __restrict__ sumh, float* __restrict__ agg,
        const int* __restrict__ flags, int E) {
    __shared__ float smax[8];
    __shared__ float wsum[4][8];
    int tid = threadIdx.x;
    if (tid < 8) smax[tid] = maxh[tid];
    __syncthreads();
    int idx64 = flags[0];
    int e = blockIdx.x * 256 + tid;
    float w[8];
    if (e < E) {
        const float4* ap = (const float4*)(alpha + (size_t)e * 8);
        float4 a0 = ap[0], a1 = ap[1];
        w[0] = expf(a0.x - smax[0]); w[1] = expf(a0.y - smax[1]);
        w[2] = expf(a0.z - smax[2]); w[3] = expf(a0.w - smax[3]);
        w[4] = expf(a1.x - smax[4]); w[5] = expf(a1.y - smax[5]);
        w[6] = expf(a1.z - smax[6]); w[7] = expf(a1.w - smax[7]);
        int d;
        if (idx64) d = ei[2 * ((size_t)E + e)];
        else       d = ei[(size_t)E + e];
        const float4* gd = (const float4*)(g + (size_t)d * 64);
        float* aggd = agg + (size_t)d * 64;
#pragma unroll
        for (int h = 0; h < 8; ++h) {
            float4 b0 = gd[h * 2], b1 = gd[h * 2 + 1];
            float ww = w[h];
            atomicAdd(aggd + h * 8 + 0, b0.x * ww);
            atomicAdd(aggd + h * 8 + 1, b0.y * ww);
            atomicAdd(aggd + h * 8 + 2, b0.z * ww);
            atomicAdd(aggd + h * 8 + 3, b0.w * ww);
            atomicAdd(aggd + h * 8 + 4, b1.x * ww);
            atomicAdd(aggd + h * 8 + 5, b1.y * ww);
            atomicAdd(aggd + h * 8 + 6, b1.z * ww);
            atomicAdd(aggd + h * 8 + 7, b1.w * ww);
        }
    } else {
#pragma unroll
        for (int h = 0; h < 8; ++h) w[h] = 0.f;
    }
    // block-reduced per-head denominator
#pragma unroll
    for (int h = 0; h < 8; ++h) {
        float s = w[h];
#pragma unroll
        for (int off = 32; off >= 1; off >>= 1)
            s += __shfl_xor(s, off, 64);
        w[h] = s;
    }
    int wave = tid >> 6, lane = tid & 63;
    if (lane == 0)
#pragma unroll
        for (int h = 0; h < 8; ++h) wsum[wave][h] = w[h];
    __syncthreads();
    if (tid < 8)
        atomicAdd(&sumh[tid], wsum[0][tid] + wsum[1][tid] + wsum[2][tid] + wsum[3][tid]);
}

// ---------------------------------------------------------------- K4: out = relu((agg / sum_h) @ W_out.T)  -> fp32
__global__ __launch_bounds__(256) void out_kernel(
        const float* __restrict__ agg, const float* __restrict__ W_out,
        const float* __restrict__ sumh, float* __restrict__ out, int N) {
    __shared__ float sSum[8];
    __shared__ float sWo[8 * 65];     // +1 pad
    __shared__ float sAgg[32 * 65];   // +1 pad
    int tid = threadIdx.x;
    if (tid < 8) sSum[tid] = sumh[tid];
    __syncthreads();
    for (int idx = tid; idx < 512; idx += 256) {
        int k = idx >> 6, j = idx & 63;
        sWo[k * 65 + j] = W_out[idx] / sSum[j >> 3];   // fold softmax denom into weights
    }
    int nbase = blockIdx.x * 32;
    for (int idx = tid; idx < 2048; idx += 256) {
        int nl = idx >> 6, j = idx & 63;
        int n = nbase + nl;
        sAgg[nl * 65 + j] = (n < N) ? agg[(size_t)n * 64 + j] : 0.f;
    }
    __syncthreads();
    int nl = tid >> 3, k = tid & 7;
    int n = nbase + nl;
    if (n < N) {
        float acc = 0.f;
#pragma unroll
        for (int j = 0; j < 64; ++j) acc += sAgg[nl * 65 + j] * sWo[k * 65 + j];
        out[(size_t)n * 8 + k] = (acc > 0.f) ? acc : 0.f;
    }
}

extern "C" void kernel_launch(void* const* d_in, const int* in_sizes, int n_in,
                              void* d_out, int out_size, void* d_ws, size_t ws_size,
                              hipStream_t stream) {
    const float* x          = (const float*)d_in[0];
    const float* edge_attr  = (const float*)d_in[1];
    const float* W          = (const float*)d_in[2];
    const float* W_edge     = (const float*)d_in[3];
    const float* W_edge_att = (const float*)d_in[4];
    const float* W_att      = (const float*)d_in[5];
    const float* W_out      = (const float*)d_in[6];
    const int*   ei         = (const int*)d_in[7];
    float* out = (float*)d_out;

    int N = in_sizes[0] / 128;   // 50000
    int E = in_sizes[1] / 16;    // 800000

    float* ws    = (float*)d_ws;
    float* G     = ws;                           // 8192
    float* M     = ws + 8192;                    // 128
    float* maxh  = ws + 8320;                    // 8
    float* sumh  = ws + 8328;                    // 8
    int*   flags = (int*)(ws + 8336);            // 1
    float* g     = ws + 8448;                    // N*64
    float* alpha = g + (size_t)N * 64;           // E*8
    float* agg   = alpha + (size_t)E * 8;        // N*64
    // total ~51.3 MB of ws

    hipLaunchKernelGGL(init_kernel, dim3(1), dim3(256), 0, stream,
                       W, W_edge, W_edge_att, W_att, ei, G, M, maxh, sumh, flags);
    hipLaunchKernelGGL(g_kernel, dim3((N + 15) / 16), dim3(256), 0, stream,
                       x, G, g, agg, N);
    hipLaunchKernelGGL(edge1_kernel, dim3((E + 255) / 256), dim3(256), 0, stream,
                       edge_attr, ei, M, g, alpha, maxh, flags, E);
    hipLaunchKernelGGL(edge2_kernel, dim3((E + 255) / 256), dim3(256), 0, stream,
                       ei, g, alpha, maxh, sumh, agg, flags, E);
    hipLaunchKernelGGL(out_kernel, dim3((N + 31) / 32), dim3(256), 0, stream,
                       agg, W_out, sumh, out, N);
}

// Round 3
// 503.654 us; speedup vs baseline: 5.8171x; 5.8171x over previous
//
#include <hip/hip_runtime.h>
#include <hip/hip_bf16.h>

// ---------------------------------------------------------------- K0: init
// M[8][16] = W_edge_att(8x64) @ W_edge(64x16)
// G[64][128]: G[h*8+k][i] = sum_d W[(h*8+d)*128+i] * W_att[k*8+d]
// Also: probe edge_index for int64 layout (odd int32 words all zero).
__global__ __launch_bounds__(256) void init_kernel(
        const float* __restrict__ W, const float* __restrict__ W_edge,
        const float* __restrict__ W_edge_att, const float* __restrict__ W_att,
        const int* __restrict__ ei,
        float* __restrict__ G, float* __restrict__ M,
        float* __restrict__ sumh, int* __restrict__ flags) {
    int tid = threadIdx.x;
    if (tid < 128) {
        int h = tid >> 4, k = tid & 15;
        float acc = 0.f;
        for (int j = 0; j < 64; ++j)
            acc += W_edge_att[h * 64 + j] * W_edge[j * 16 + k];
        M[tid] = acc;
    }
    for (int idx = tid; idx < 64 * 128; idx += 256) {
        int l = idx >> 7, i = idx & 127;
        int h = l >> 3, k = l & 7;
        float acc = 0.f;
#pragma unroll
        for (int d = 0; d < 8; ++d)
            acc += W[(h * 8 + d) * 128 + i] * W_att[k * 8 + d];
        G[idx] = acc;
    }
    if (tid < 8) sumh[tid] = 0.f;
    if (tid == 0) {
        // int64 edge_index (values < 2^31): every odd int32 word is 0.
        int zc = 0;
        for (int i = 1; i < 128; i += 2) zc += (ei[i] == 0);
        flags[0] = (zc >= 60) ? 1 : 0;
    }
}

// ---------------------------------------------------------------- K1: g = x @ G.T  (+ zero S)
__global__ __launch_bounds__(256) void g_kernel(
        const float* __restrict__ x, const float* __restrict__ G,
        float* __restrict__ g, float* __restrict__ S, int N) {
    __shared__ float sG[64 * 129];   // +1 pad: kills stride-128 bank conflict
    __shared__ float sx[16 * 128];
    int tid = threadIdx.x;
    for (int idx = tid; idx < 64 * 128; idx += 256)
        sG[(idx >> 7) * 129 + (idx & 127)] = G[idx];
    int nbase = blockIdx.x * 16;
    {
        int i8 = tid * 8;                 // 2048 floats, 8 per thread
        int n = nbase + (i8 >> 7);
        if (n < N) {
            const float4* p = (const float4*)(x + (size_t)n * 128 + (i8 & 127));
            float4 v0 = p[0], v1 = p[1];
            sx[i8 + 0] = v0.x; sx[i8 + 1] = v0.y; sx[i8 + 2] = v0.z; sx[i8 + 3] = v0.w;
            sx[i8 + 4] = v1.x; sx[i8 + 5] = v1.y; sx[i8 + 6] = v1.z; sx[i8 + 7] = v1.w;
        } else {
#pragma unroll
            for (int j = 0; j < 8; ++j) sx[i8 + j] = 0.f;
        }
    }
    __syncthreads();
    for (int o = tid; o < 16 * 64; o += 256) {
        int nl = o >> 6, l = o & 63;
        int n = nbase + nl;
        if (n >= N) continue;
        float acc = 0.f;
        const float* gr = &sG[l * 129];
        const float* xr = &sx[nl * 128];
#pragma unroll
        for (int i = 0; i < 128; ++i) acc += xr[i] * gr[i];
        g[(size_t)n * 64 + l] = acc;
        if (l < 8) S[(size_t)n * 8 + l] = 0.f;   // zero S (harness poisons ws)
    }
}

// ---------------------------------------------------------------- K2: fused edge pass
// w_eh = exp(leaky_relu(g_src.g_dst + 8*ea))  (no max shift: |alpha| <~ 50, exp fits fp32)
// S[dst][h] += w_eh  (8 atomics/edge, replaces 64);  sumh[h] += w_eh (block-reduced)
__global__ __launch_bounds__(256) void edge_kernel(
        const float* __restrict__ edge_attr, const int* __restrict__ ei,
        const float* __restrict__ M, const float* __restrict__ g,
        float* __restrict__ S, float* __restrict__ sumh,
        const int* __restrict__ flags, int E) {
    __shared__ float sM[128];
    __shared__ float wsum[4][8];
    int tid = threadIdx.x;
    if (tid < 128) sM[tid] = M[tid];
    __syncthreads();
    int idx64 = flags[0];
    int e = blockIdx.x * 256 + tid;
    float w[8];
    if (e < E) {
        float at[16];
        const float4* p = (const float4*)(edge_attr + (size_t)e * 16);
        float4 v0 = p[0], v1 = p[1], v2 = p[2], v3 = p[3];
        at[0] = v0.x; at[1] = v0.y; at[2] = v0.z; at[3] = v0.w;
        at[4] = v1.x; at[5] = v1.y; at[6] = v1.z; at[7] = v1.w;
        at[8] = v2.x; at[9] = v2.y; at[10] = v2.z; at[11] = v2.w;
        at[12] = v3.x; at[13] = v3.y; at[14] = v3.z; at[15] = v3.w;
        int s, d;
        if (idx64) { s = ei[2 * (size_t)e]; d = ei[2 * ((size_t)E + e)]; }
        else       { s = ei[e];             d = ei[(size_t)E + e]; }
        const float4* gs = (const float4*)(g + (size_t)s * 64);
        const float4* gd = (const float4*)(g + (size_t)d * 64);
        float* Sd = S + (size_t)d * 8;
#pragma unroll
        for (int h = 0; h < 8; ++h) {
            float ea = 0.f;
#pragma unroll
            for (int k = 0; k < 16; ++k) ea += sM[h * 16 + k] * at[k];
            float4 a0 = gs[h * 2], a1 = gs[h * 2 + 1];
            float4 b0 = gd[h * 2], b1 = gd[h * 2 + 1];
            float dot = a0.x * b0.x + a0.y * b0.y + a0.z * b0.z + a0.w * b0.w
                      + a1.x * b1.x + a1.y * b1.y + a1.z * b1.z + a1.w * b1.w;
            float t = dot + 8.f * ea;                  // edge_term = ea * D
            t = (t > 0.f) ? t : 0.2f * t;              // leaky_relu(0.2)
            w[h] = expf(t);
            atomicAdd(Sd + h, w[h]);
        }
    } else {
#pragma unroll
        for (int h = 0; h < 8; ++h) w[h] = 0.f;
    }
    // block-reduced per-head softmax denominator
#pragma unroll
    for (int h = 0; h < 8; ++h) {
        float s = w[h];
#pragma unroll
        for (int off = 32; off >= 1; off >>= 1)
            s += __shfl_xor(s, off, 64);
        w[h] = s;
    }
    int wave = tid >> 6, lane = tid & 63;
    if (lane == 0)
#pragma unroll
        for (int h = 0; h < 8; ++h) wsum[wave][h] = w[h];
    __syncthreads();
    if (tid < 8)
        atomicAdd(&sumh[tid], wsum[0][tid] + wsum[1][tid] + wsum[2][tid] + wsum[3][tid]);
}

// ---------------------------------------------------------------- K3: out = relu(((g .* S_broadcast) / sum_h) @ W_out.T)
__global__ __launch_bounds__(256) void out_kernel(
        const float* __restrict__ g, const float* __restrict__ S,
        const float* __restrict__ W_out, const float* __restrict__ sumh,
        float* __restrict__ out, int N) {
    __shared__ float sWo[8 * 65];     // +1 pad
    __shared__ float sAgg[32 * 65];   // +1 pad
    int tid = threadIdx.x;
    __shared__ float sSum[8];
    if (tid < 8) sSum[tid] = sumh[tid];
    __syncthreads();
    for (int idx = tid; idx < 512; idx += 256) {
        int k = idx >> 6, j = idx & 63;
        sWo[k * 65 + j] = W_out[idx] / sSum[j >> 3];   // fold softmax denom into weights
    }
    int nbase = blockIdx.x * 32;
    for (int idx = tid; idx < 2048; idx += 256) {
        int nl = idx >> 6, j = idx & 63;
        int n = nbase + nl;
        // agg[n,j] = g[n,j] * S[n, j>>3]
        sAgg[nl * 65 + j] = (n < N) ? g[(size_t)n * 64 + j] * S[(size_t)n * 8 + (j >> 3)]
                                    : 0.f;
    }
    __syncthreads();
    int nl = tid >> 3, k = tid & 7;
    int n = nbase + nl;
    if (n < N) {
        float acc = 0.f;
#pragma unroll
        for (int j = 0; j < 64; ++j) acc += sAgg[nl * 65 + j] * sWo[k * 65 + j];
        out[(size_t)n * 8 + k] = (acc > 0.f) ? acc : 0.f;
    }
}

extern "C" void kernel_launch(void* const* d_in, const int* in_sizes, int n_in,
                              void* d_out, int out_size, void* d_ws, size_t ws_size,
                              hipStream_t stream) {
    const float* x          = (const float*)d_in[0];
    const float* edge_attr  = (const float*)d_in[1];
    const float* W          = (const float*)d_in[2];
    const float* W_edge     = (const float*)d_in[3];
    const float* W_edge_att = (const float*)d_in[4];
    const float* W_att      = (const float*)d_in[5];
    const float* W_out      = (const float*)d_in[6];
    const int*   ei         = (const int*)d_in[7];
    float* out = (float*)d_out;

    int N = in_sizes[0] / 128;   // 50000
    int E = in_sizes[1] / 16;    // 800000

    float* ws    = (float*)d_ws;
    float* G     = ws;                           // 8192
    float* M     = ws + 8192;                    // 128
    float* sumh  = ws + 8320;                    // 8
    int*   flags = (int*)(ws + 8328);            // 1
    float* g     = ws + 8448;                    // N*64
    float* S     = g + (size_t)N * 64;           // N*8
    // total ~14.4 MB of ws

    hipLaunchKernelGGL(init_kernel, dim3(1), dim3(256), 0, stream,
                       W, W_edge, W_edge_att, W_att, ei, G, M, sumh, flags);
    hipLaunchKernelGGL(g_kernel, dim3((N + 15) / 16), dim3(256), 0, stream,
                       x, G, g, S, N);
    hipLaunchKernelGGL(edge_kernel, dim3((E + 255) / 256), dim3(256), 0, stream,
                       edge_attr, ei, M, g, S, sumh, flags, E);
    hipLaunchKernelGGL(out_kernel, dim3((N + 31) / 32), dim3(256), 0, stream,
                       g, S, W_out, sumh, out, N);
}

// Round 4
// 270.104 us; speedup vs baseline: 10.8470x; 1.8647x over previous
//
#include <hip/hip_runtime.h>
#include <hip/hip_bf16.h>

// ---------------------------------------------------------------- K0: init
// Mt[16][8]: Mt[k][h] = (W_edge_att @ W_edge)[h][k]   (transposed for LDS)
// G[64][128]: G[h*8+k][i] = sum_d W[(h*8+d)*128+i] * W_att[k*8+d]
// Also: probe edge_index for int64 layout (odd int32 words all zero).
__global__ __launch_bounds__(256) void init_kernel(
        const float* __restrict__ W, const float* __restrict__ W_edge,
        const float* __restrict__ W_edge_att, const float* __restrict__ W_att,
        const int* __restrict__ ei,
        float* __restrict__ G, float* __restrict__ Mt,
        float* __restrict__ sumh, int* __restrict__ flags) {
    int tid = threadIdx.x;
    if (tid < 128) {
        int h = tid >> 4, k = tid & 15;
        float acc = 0.f;
        for (int j = 0; j < 64; ++j)
            acc += W_edge_att[h * 64 + j] * W_edge[j * 16 + k];
        Mt[k * 8 + h] = acc;
    }
    for (int idx = tid; idx < 64 * 128; idx += 256) {
        int l = idx >> 7, i = idx & 127;
        int h = l >> 3, k = l & 7;
        float acc = 0.f;
#pragma unroll
        for (int d = 0; d < 8; ++d)
            acc += W[(h * 8 + d) * 128 + i] * W_att[k * 8 + d];
        G[idx] = acc;
    }
    if (tid < 8) sumh[tid] = 0.f;
    if (tid == 0) {
        // int64 edge_index (values < 2^31): every odd int32 word is 0.
        int zc = 0;
        for (int i = 1; i < 128; i += 2) zc += (ei[i] == 0);
        flags[0] = (zc >= 60) ? 1 : 0;
    }
}

// ---------------------------------------------------------------- K1: g = x @ G.T  (+ zero S)
__global__ __launch_bounds__(256) void g_kernel(
        const float* __restrict__ x, const float* __restrict__ G,
        float* __restrict__ g, float* __restrict__ S, int N) {
    __shared__ float sG[64 * 129];   // +1 pad: kills stride-128 bank conflict
    __shared__ float sx[16 * 128];
    int tid = threadIdx.x;
    for (int idx = tid; idx < 64 * 128; idx += 256)
        sG[(idx >> 7) * 129 + (idx & 127)] = G[idx];
    int nbase = blockIdx.x * 16;
    {
        int i8 = tid * 8;                 // 2048 floats, 8 per thread
        int n = nbase + (i8 >> 7);
        if (n < N) {
            const float4* p = (const float4*)(x + (size_t)n * 128 + (i8 & 127));
            float4 v0 = p[0], v1 = p[1];
            sx[i8 + 0] = v0.x; sx[i8 + 1] = v0.y; sx[i8 + 2] = v0.z; sx[i8 + 3] = v0.w;
            sx[i8 + 4] = v1.x; sx[i8 + 5] = v1.y; sx[i8 + 6] = v1.z; sx[i8 + 7] = v1.w;
        } else {
#pragma unroll
            for (int j = 0; j < 8; ++j) sx[i8 + j] = 0.f;
        }
    }
    __syncthreads();
    for (int o = tid; o < 16 * 64; o += 256) {
        int nl = o >> 6, l = o & 63;
        int n = nbase + nl;
        if (n >= N) continue;
        float acc = 0.f;
        const float* gr = &sG[l * 129];
        const float* xr = &sx[nl * 128];
#pragma unroll
        for (int i = 0; i < 128; ++i) acc += xr[i] * gr[i];
        g[(size_t)n * 64 + l] = acc;
        if (l < 8) S[(size_t)n * 8 + l] = 0.f;   // zero S (harness poisons ws)
    }
}

// ---------------------------------------------------------------- K2: fused edge pass, (edge x head) per lane
// lane h of an 8-lane group handles head h of one edge:
//   w = exp(leaky_relu(g_src[h].g_dst[h] + 8*ea_h));  S[dst][h] += w (HW atomic)
#define EDGE_ITER 4
__global__ __launch_bounds__(256) void edge_kernel(
        const float* __restrict__ edge_attr, const int* __restrict__ ei,
        const float* __restrict__ Mt, const float* __restrict__ g,
        float* __restrict__ S, float* __restrict__ sumh,
        const int* __restrict__ flags, int E) {
    __shared__ float sMt[128];        // Mt[k][h]: per-k reads hit 8 distinct banks
    __shared__ float wsum[4][8];
    int tid = threadIdx.x;
    if (tid < 128) sMt[tid] = Mt[tid];
    __syncthreads();
    int idx64 = flags[0];
    int h = tid & 7;                  // head
    int grp = tid >> 3;               // 32 groups per block
    float wacc = 0.f;
    int ebase = blockIdx.x * (32 * EDGE_ITER);
#pragma unroll
    for (int it = 0; it < EDGE_ITER; ++it) {
        int e = ebase + it * 32 + grp;
        if (e < E) {
            int s, d;
            if (idx64) { s = ei[2 * (size_t)e]; d = ei[2 * ((size_t)E + e)]; }
            else       { s = ei[e];             d = ei[(size_t)E + e]; }
            // ea_h = sum_k Mt[k][h] * edge_attr[e][k]  (attr loads broadcast in group)
            const float4* p = (const float4*)(edge_attr + (size_t)e * 16);
            float4 v0 = p[0], v1 = p[1], v2 = p[2], v3 = p[3];
            float ea =
                sMt[0*8+h]*v0.x + sMt[1*8+h]*v0.y + sMt[2*8+h]*v0.z + sMt[3*8+h]*v0.w +
                sMt[4*8+h]*v1.x + sMt[5*8+h]*v1.y + sMt[6*8+h]*v1.z + sMt[7*8+h]*v1.w +
                sMt[8*8+h]*v2.x + sMt[9*8+h]*v2.y + sMt[10*8+h]*v2.z + sMt[11*8+h]*v2.w +
                sMt[12*8+h]*v3.x + sMt[13*8+h]*v3.y + sMt[14*8+h]*v3.z + sMt[15*8+h]*v3.w;
            // head fragment gathers: 8 lanes cover the contiguous 256B row
            const float4* gs = (const float4*)(g + (size_t)s * 64 + h * 8);
            const float4* gd = (const float4*)(g + (size_t)d * 64 + h * 8);
            float4 a0 = gs[0], a1 = gs[1];
            float4 b0 = gd[0], b1 = gd[1];
            float dot = a0.x * b0.x + a0.y * b0.y + a0.z * b0.z + a0.w * b0.w
                      + a1.x * b1.x + a1.y * b1.y + a1.z * b1.z + a1.w * b1.w;
            float t = dot + 8.f * ea;                  // edge_term = ea * D
            t = (t > 0.f) ? t : 0.2f * t;              // leaky_relu(0.2)
            float w = expf(t);
            unsafeAtomicAdd(S + (size_t)d * 8 + h, w); // HW global_atomic_add_f32
            wacc += w;
        }
    }
    // reduce wacc over lanes with equal (lane&7) -> per-head partials in lanes 0..7
    wacc += __shfl_xor(wacc, 8, 64);
    wacc += __shfl_xor(wacc, 16, 64);
    wacc += __shfl_xor(wacc, 32, 64);
    int wave = tid >> 6, lane = tid & 63;
    if (lane < 8) wsum[wave][lane] = wacc;
    __syncthreads();
    if (tid < 8)
        unsafeAtomicAdd(&sumh[tid], wsum[0][tid] + wsum[1][tid] + wsum[2][tid] + wsum[3][tid]);
}

// ---------------------------------------------------------------- K3: out = relu(((g .* S_broadcast) / sum_h) @ W_out.T)
__global__ __launch_bounds__(256) void out_kernel(
        const float* __restrict__ g, const float* __restrict__ S,
        const float* __restrict__ W_out, const float* __restrict__ sumh,
        float* __restrict__ out, int N) {
    __shared__ float sWo[8 * 65];     // +1 pad
    __shared__ float sAgg[32 * 65];   // +1 pad
    __shared__ float sSum[8];
    int tid = threadIdx.x;
    if (tid < 8) sSum[tid] = sumh[tid];
    __syncthreads();
    for (int idx = tid; idx < 512; idx += 256) {
        int k = idx >> 6, j = idx & 63;
        sWo[k * 65 + j] = W_out[idx] / sSum[j >> 3];   // fold softmax denom into weights
    }
    int nbase = blockIdx.x * 32;
    for (int idx = tid; idx < 2048; idx += 256) {
        int nl = idx >> 6, j = idx & 63;
        int n = nbase + nl;
        // agg[n,j] = g[n,j] * S[n, j>>3]
        sAgg[nl * 65 + j] = (n < N) ? g[(size_t)n * 64 + j] * S[(size_t)n * 8 + (j >> 3)]
                                    : 0.f;
    }
    __syncthreads();
    int nl = tid >> 3, k = tid & 7;
    int n = nbase + nl;
    if (n < N) {
        float acc = 0.f;
#pragma unroll
        for (int j = 0; j < 64; ++j) acc += sAgg[nl * 65 + j] * sWo[k * 65 + j];
        out[(size_t)n * 8 + k] = (acc > 0.f) ? acc : 0.f;
    }
}

extern "C" void kernel_launch(void* const* d_in, const int* in_sizes, int n_in,
                              void* d_out, int out_size, void* d_ws, size_t ws_size,
                              hipStream_t stream) {
    const float* x          = (const float*)d_in[0];
    const float* edge_attr  = (const float*)d_in[1];
    const float* W          = (const float*)d_in[2];
    const float* W_edge     = (const float*)d_in[3];
    const float* W_edge_att = (const float*)d_in[4];
    const float* W_att      = (const float*)d_in[5];
    const float* W_out      = (const float*)d_in[6];
    const int*   ei         = (const int*)d_in[7];
    float* out = (float*)d_out;

    int N = in_sizes[0] / 128;   // 50000
    int E = in_sizes[1] / 16;    // 800000

    float* ws    = (float*)d_ws;
    float* G     = ws;                           // 8192
    float* Mt    = ws + 8192;                    // 128
    float* sumh  = ws + 8320;                    // 8
    int*   flags = (int*)(ws + 8328);            // 1
    float* g     = ws + 8448;                    // N*64
    float* S     = g + (size_t)N * 64;           // N*8
    // total ~14.4 MB of ws

    hipLaunchKernelGGL(init_kernel, dim3(1), dim3(256), 0, stream,
                       W, W_edge, W_edge_att, W_att, ei, G, Mt, sumh, flags);
    hipLaunchKernelGGL(g_kernel, dim3((N + 15) / 16), dim3(256), 0, stream,
                       x, G, g, S, N);
    int epb = 32 * EDGE_ITER;   // 128 edges per block
    hipLaunchKernelGGL(edge_kernel, dim3((E + epb - 1) / epb), dim3(256), 0, stream,
                       edge_attr, ei, Mt, g, S, sumh, flags, E);
    hipLaunchKernelGGL(out_kernel, dim3((N + 31) / 32), dim3(256), 0, stream,
                       g, S, W_out, sumh, out, N);
}

// Round 5
// 223.378 us; speedup vs baseline: 13.1159x; 1.2092x over previous
//
#include <hip/hip_runtime.h>
#include <hip/hip_bf16.h>

// ---------------------------------------------------------------- K0: init
// Mt[16][8]: Mt[k][h] = (W_edge_att @ W_edge)[h][k]   (transposed for LDS)
// G[64][128]: G[h*8+k][i] = sum_d W[(h*8+d)*128+i] * W_att[k*8+d]
// Also: probe edge_index for int64 layout (odd int32 words all zero).
__global__ __launch_bounds__(256) void init_kernel(
        const float* __restrict__ W, const float* __restrict__ W_edge,
        const float* __restrict__ W_edge_att, const float* __restrict__ W_att,
        const int* __restrict__ ei,
        float* __restrict__ G, float* __restrict__ Mt,
        float* __restrict__ sumh, int* __restrict__ flags) {
    int tid = threadIdx.x;
    if (tid < 128) {
        int h = tid >> 4, k = tid & 15;
        float acc = 0.f;
        for (int j = 0; j < 64; ++j)
            acc += W_edge_att[h * 64 + j] * W_edge[j * 16 + k];
        Mt[k * 8 + h] = acc;
    }
    for (int idx = tid; idx < 64 * 128; idx += 256) {
        int l = idx >> 7, i = idx & 127;
        int h = l >> 3, k = l & 7;
        float acc = 0.f;
#pragma unroll
        for (int d = 0; d < 8; ++d)
            acc += W[(h * 8 + d) * 128 + i] * W_att[k * 8 + d];
        G[idx] = acc;
    }
    if (tid < 8) sumh[tid] = 0.f;
    if (tid == 0) {
        int zc = 0;
        for (int i = 1; i < 128; i += 2) zc += (ei[i] == 0);
        flags[0] = (zc >= 60) ? 1 : 0;
    }
}

// ---------------------------------------------------------------- K1: g = x @ G.T  (+ zero S)
// 32 rows/block, 8 rows/wave. Lane l owns output column l.
// Inner loop: 1 float4 G-fragment (register-cached across 8 rows) +
// 8 broadcast float4 x reads + 32 FMA -> FMA-bound, not LDS-issue-bound.
__global__ __launch_bounds__(256) void g_kernel(
        const float* __restrict__ x, const float* __restrict__ G,
        float* __restrict__ g, float* __restrict__ S, int N) {
    __shared__ float sG[64 * 132];    // stride 132: 16B-aligned f4, banks spread
    __shared__ float sx[32 * 128];
    int tid = threadIdx.x;
    for (int f4 = tid; f4 < 2048; f4 += 256) {          // G: 8192 floats
        int l = f4 >> 5, i4 = f4 & 31;
        *(float4*)&sG[l * 132 + i4 * 4] = ((const float4*)G)[f4];
    }
    int nbase = blockIdx.x * 32;
    for (int f4 = tid; f4 < 32 * 32; f4 += 256) {       // x: 32 rows
        int nl = f4 >> 5, i4 = f4 & 31;
        int n = nbase + nl;
        float4 v = (n < N) ? ((const float4*)(x + (size_t)n * 128))[i4]
                           : make_float4(0.f, 0.f, 0.f, 0.f);
        *(float4*)&sx[nl * 128 + i4 * 4] = v;
    }
    __syncthreads();
    int wave = tid >> 6, l = tid & 63;
    int r0 = wave * 8;
    float acc[8];
#pragma unroll
    for (int r = 0; r < 8; ++r) acc[r] = 0.f;
    const float* gR = &sG[l * 132];
#pragma unroll 4
    for (int i = 0; i < 128; i += 4) {
        float4 gv = *(const float4*)(gR + i);
#pragma unroll
        for (int r = 0; r < 8; ++r) {
            float4 xv = *(const float4*)&sx[(r0 + r) * 128 + i];  // wave-broadcast
            acc[r] += gv.x * xv.x + gv.y * xv.y + gv.z * xv.z + gv.w * xv.w;
        }
    }
#pragma unroll
    for (int r = 0; r < 8; ++r) {
        int n = nbase + r0 + r;
        if (n < N) {
            g[(size_t)n * 64 + l] = acc[r];
            if (l < 8) S[(size_t)n * 8 + l] = 0.f;   // zero S (harness poisons ws)
        }
    }
}

// ---------------------------------------------------------------- K2: fused edge pass, (edge x head) per lane
// lane h of an 8-lane group handles head h of one edge:
//   w = exp(leaky_relu(g_src[h].g_dst[h] + 8*ea_h));  S[dst][h] += w (HW atomic)
#define EDGE_ITER 8
__global__ __launch_bounds__(256) void edge_kernel(
        const float* __restrict__ edge_attr, const int* __restrict__ ei,
        const float* __restrict__ Mt, const float* __restrict__ g,
        float* __restrict__ S, float* __restrict__ sumh,
        const int* __restrict__ flags, int E) {
    __shared__ float sMt[128];        // Mt[k][h]
    __shared__ float wsum[4][8];
    int tid = threadIdx.x;
    if (tid < 128) sMt[tid] = Mt[tid];
    __syncthreads();
    int idx64 = flags[0];
    int h = tid & 7;                  // head
    int grp = tid >> 3;               // 32 groups per block
    int ebase = blockIdx.x * (32 * EDGE_ITER);

    // prefetch all indices first: 2*EDGE_ITER independent loads in flight
    int sIdx[EDGE_ITER], dIdx[EDGE_ITER];
    if (idx64) {
        const long long* ei64 = (const long long*)ei;
#pragma unroll
        for (int it = 0; it < EDGE_ITER; ++it) {
            int e = ebase + it * 32 + grp;
            sIdx[it] = (e < E) ? (int)ei64[e] : 0;
            dIdx[it] = (e < E) ? (int)ei64[(size_t)E + e] : 0;
        }
    } else {
#pragma unroll
        for (int it = 0; it < EDGE_ITER; ++it) {
            int e = ebase + it * 32 + grp;
            sIdx[it] = (e < E) ? ei[e] : 0;
            dIdx[it] = (e < E) ? ei[(size_t)E + e] : 0;
        }
    }

    float wacc = 0.f;
#pragma unroll
    for (int it = 0; it < EDGE_ITER; ++it) {
        int e = ebase + it * 32 + grp;
        if (e < E) {
            const float4* p = (const float4*)(edge_attr + (size_t)e * 16);
            const float4* gs = (const float4*)(g + (size_t)sIdx[it] * 64 + h * 8);
            const float4* gd = (const float4*)(g + (size_t)dIdx[it] * 64 + h * 8);
            float4 a0 = gs[0], a1 = gs[1];
            float4 b0 = gd[0], b1 = gd[1];
            float4 v0 = p[0], v1 = p[1], v2 = p[2], v3 = p[3];
            float ea =
                sMt[0*8+h]*v0.x + sMt[1*8+h]*v0.y + sMt[2*8+h]*v0.z + sMt[3*8+h]*v0.w +
                sMt[4*8+h]*v1.x + sMt[5*8+h]*v1.y + sMt[6*8+h]*v1.z + sMt[7*8+h]*v1.w +
                sMt[8*8+h]*v2.x + sMt[9*8+h]*v2.y + sMt[10*8+h]*v2.z + sMt[11*8+h]*v2.w +
                sMt[12*8+h]*v3.x + sMt[13*8+h]*v3.y + sMt[14*8+h]*v3.z + sMt[15*8+h]*v3.w;
            float dot = a0.x * b0.x + a0.y * b0.y + a0.z * b0.z + a0.w * b0.w
                      + a1.x * b1.x + a1.y * b1.y + a1.z * b1.z + a1.w * b1.w;
            float t = dot + 8.f * ea;                  // edge_term = ea * D
            t = (t > 0.f) ? t : 0.2f * t;              // leaky_relu(0.2)
            float w = expf(t);
            unsafeAtomicAdd(S + (size_t)dIdx[it] * 8 + h, w);
            wacc += w;
        }
    }
    // reduce wacc over lanes with equal (lane&7) -> per-head partials in lanes 0..7
    wacc += __shfl_xor(wacc, 8, 64);
    wacc += __shfl_xor(wacc, 16, 64);
    wacc += __shfl_xor(wacc, 32, 64);
    int wave = tid >> 6, lane = tid & 63;
    if (lane < 8) wsum[wave][lane] = wacc;
    __syncthreads();
    if (tid < 8)
        unsafeAtomicAdd(&sumh[tid], wsum[0][tid] + wsum[1][tid] + wsum[2][tid] + wsum[3][tid]);
}

// ---------------------------------------------------------------- K3: out = relu(((g .* S_broadcast) / sum_h) @ W_out.T)
__global__ __launch_bounds__(256) void out_kernel(
        const float* __restrict__ g, const float* __restrict__ S,
        const float* __restrict__ W_out, const float* __restrict__ sumh,
        float* __restrict__ out, int N) {
    __shared__ float sWo[8 * 68];     // stride 68: f4-aligned, banks spread
    __shared__ float sAgg[32 * 68];
    __shared__ float sSum[8];
    int tid = threadIdx.x;
    if (tid < 8) sSum[tid] = sumh[tid];
    __syncthreads();
    for (int idx = tid; idx < 512; idx += 256) {
        int k = idx >> 6, j = idx & 63;
        sWo[k * 68 + j] = W_out[idx] / sSum[j >> 3];   // fold softmax denom
    }
    int nbase = blockIdx.x * 32;
    for (int f4 = tid; f4 < 512; f4 += 256) {          // 32 rows x 16 float4
        int nl = f4 >> 4, j4 = f4 & 15;
        int n = nbase + nl;
        float4 v = make_float4(0.f, 0.f, 0.f, 0.f);
        if (n < N) {
            float sv = S[(size_t)n * 8 + (j4 >> 1)];
            float4 gv = ((const float4*)(g + (size_t)n * 64))[j4];
            v = make_float4(gv.x * sv, gv.y * sv, gv.z * sv, gv.w * sv);
        }
        *(float4*)&sAgg[nl * 68 + j4 * 4] = v;
    }
    __syncthreads();
    int nl = tid >> 3, k = tid & 7;
    int n = nbase + nl;
    float acc = 0.f;
#pragma unroll
    for (int j = 0; j < 64; j += 4) {
        float4 av = *(const float4*)&sAgg[nl * 68 + j];
        float4 wv = *(const float4*)&sWo[k * 68 + j];
        acc += av.x * wv.x + av.y * wv.y + av.z * wv.z + av.w * wv.w;
    }
    if (n < N)
        out[(size_t)n * 8 + k] = (acc > 0.f) ? acc : 0.f;
}

extern "C" void kernel_launch(void* const* d_in, const int* in_sizes, int n_in,
                              void* d_out, int out_size, void* d_ws, size_t ws_size,
                              hipStream_t stream) {
    const float* x          = (const float*)d_in[0];
    const float* edge_attr  = (const float*)d_in[1];
    const float* W          = (const float*)d_in[2];
    const float* W_edge     = (const float*)d_in[3];
    const float* W_edge_att = (const float*)d_in[4];
    const float* W_att      = (const float*)d_in[5];
    const float* W_out      = (const float*)d_in[6];
    const int*   ei         = (const int*)d_in[7];
    float* out = (float*)d_out;

    int N = in_sizes[0] / 128;   // 50000
    int E = in_sizes[1] / 16;    // 800000

    float* ws    = (float*)d_ws;
    float* G     = ws;                           // 8192
    float* Mt    = ws + 8192;                    // 128
    float* sumh  = ws + 8320;                    // 8
    int*   flags = (int*)(ws + 8328);            // 1
    float* g     = ws + 8448;                    // N*64
    float* S     = g + (size_t)N * 64;           // N*8
    // total ~14.4 MB of ws

    hipLaunchKernelGGL(init_kernel, dim3(1), dim3(256), 0, stream,
                       W, W_edge, W_edge_att, W_att, ei, G, Mt, sumh, flags);
    hipLaunchKernelGGL(g_kernel, dim3((N + 31) / 32), dim3(256), 0, stream,
                       x, G, g, S, N);
    int epb = 32 * EDGE_ITER;   // 256 edges per block
    hipLaunchKernelGGL(edge_kernel, dim3((E + epb - 1) / epb), dim3(256), 0, stream,
                       edge_attr, ei, Mt, g, S, sumh, flags, E);
    hipLaunchKernelGGL(out_kernel, dim3((N + 31) / 32), dim3(256), 0, stream,
                       g, S, W_out, sumh, out, N);
}